// Round 2
// baseline (1634.885 us; speedup 1.0000x reference)
//
#include <hip/hip_runtime.h>
#include <hip/hip_bf16.h>
#include <math.h>

#define NB 4
#define NS 2048
#define ND 512
#define NH 8
#define NDK 64
#define NDV 64

typedef __attribute__((ext_vector_type(8))) short short8;
typedef __attribute__((ext_vector_type(4))) float f32x4;

__device__ __forceinline__ unsigned short f2bfu(float f) {
  // round-to-nearest-even bf16 (inputs finite)
  unsigned int u = __builtin_bit_cast(unsigned int, f);
  unsigned int rounding = 0x7fffu + ((u >> 16) & 1u);
  return (unsigned short)((u + rounding) >> 16);
}
__device__ __forceinline__ float bfu2f(unsigned short u) {
  return __builtin_bit_cast(float, (unsigned int)u << 16);
}

// ---------------- prep kernels ----------------

// x [M][512] f32 -> xcat [M][1536] bf16 = [xhi | xhi | xlo]
__global__ void k_make_xcat(const float* __restrict__ in, unsigned short* __restrict__ out,
                            int n4) {
  int i = blockIdx.x * 256 + threadIdx.x;
  if (i >= n4) return;
  int row = i >> 7, col = (i & 127) * 4;  // 512/4 = 128 chunks per row
  float4 f = reinterpret_cast<const float4*>(in)[i];
  ushort4 h, l;
  h.x = f2bfu(f.x); h.y = f2bfu(f.y); h.z = f2bfu(f.z); h.w = f2bfu(f.w);
  l.x = f2bfu(f.x - bfu2f(h.x)); l.y = f2bfu(f.y - bfu2f(h.y));
  l.z = f2bfu(f.z - bfu2f(h.z)); l.w = f2bfu(f.w - bfu2f(h.w));
  ushort4* o = reinterpret_cast<ushort4*>(out + (size_t)row * 1536);
  o[col / 4] = h;
  o[(col + 512) / 4] = h;
  o[(col + 1024) / 4] = l;
}

// W [R][C] f32 -> Wcat [C][3R] bf16 rows = [Whi^T | Wlo^T | Whi^T]
__global__ void k_transpose_split(const float* __restrict__ src, unsigned short* __restrict__ dst,
                                  int R, int C) {
  __shared__ float t[32][33];
  int bx = blockIdx.x * 32, by = blockIdx.y * 32;
  int tx = threadIdx.x, ty = threadIdx.y;
  for (int i = 0; i < 32; i += 8)
    t[ty + i][tx] = src[(size_t)(by + ty + i) * C + bx + tx];
  __syncthreads();
  for (int i = 0; i < 32; i += 8) {
    float f = t[tx][ty + i];
    unsigned short h = f2bfu(f);
    unsigned short l = f2bfu(f - bfu2f(h));
    size_t base = (size_t)(bx + ty + i) * (3 * R) + by + tx;
    dst[base] = h;
    dst[base + R] = l;
    dst[base + 2 * R] = h;
  }
}

// ---------------- NT MFMA GEMM: C = A * Bt^T + bias ----------------
// A [M][K] bf16 row-major, Bt [N][K] bf16 row-major. 64x64 tile, 256 threads.
// MODE 0: out -> hi/lo [b][h][s][dk] bf16   MODE 2: out -> hi/lo V^T [b][h][dv][s] bf16
// MODE 3: out -> f32 [M][ND]
template <int MODE>
__global__ __launch_bounds__(256) void k_gemm_nt(
    const unsigned short* __restrict__ A, const unsigned short* __restrict__ Bt,
    const float* __restrict__ bias, void* __restrict__ outp, unsigned short* __restrict__ outlo,
    int M, int N, int K) {
  __shared__ __align__(16) unsigned short As[64][88];
  __shared__ __align__(16) unsigned short Bs[64][88];
  const int tid = threadIdx.x;
  const int m0 = blockIdx.y * 64;
  const int n0 = blockIdx.x * 64;
  const int wave = tid >> 6, lane = tid & 63;
  const int lm = lane & 15, lg = lane >> 4;

  f32x4 acc[4];
  for (int n = 0; n < 4; n++) acc[n] = (f32x4){0.f, 0.f, 0.f, 0.f};

  for (int k0 = 0; k0 < K; k0 += 64) {
    for (int it = 0; it < 2; it++) {
      int c = tid + it * 256;            // 512 chunks of 8 elems = 64x64 tile
      int row = c >> 3, col = (c & 7) * 8;
      *reinterpret_cast<short8*>(&As[row][col]) =
          *reinterpret_cast<const short8*>(A + (size_t)(m0 + row) * K + k0 + col);
      *reinterpret_cast<short8*>(&Bs[row][col]) =
          *reinterpret_cast<const short8*>(Bt + (size_t)(n0 + row) * K + k0 + col);
    }
    __syncthreads();
#pragma unroll
    for (int ks = 0; ks < 2; ks++) {
      short8 a = *reinterpret_cast<const short8*>(&As[wave * 16 + lm][ks * 32 + lg * 8]);
#pragma unroll
      for (int n = 0; n < 4; n++) {
        short8 b = *reinterpret_cast<const short8*>(&Bs[n * 16 + lm][ks * 32 + lg * 8]);
        acc[n] = __builtin_amdgcn_mfma_f32_16x16x32_bf16(a, b, acc[n], 0, 0, 0);
      }
    }
    __syncthreads();
  }

#pragma unroll
  for (int n = 0; n < 4; n++) {
    int gn = n0 + n * 16 + lm;
    float bv = bias[gn];
#pragma unroll
    for (int r = 0; r < 4; r++) {
      int gm = m0 + wave * 16 + lg * 4 + r;
      float v = acc[n][r] + bv;
      if (MODE == 3) {
        reinterpret_cast<float*>(outp)[(size_t)gm * ND + gn] = v;
      } else {
        int b = gm >> 11, s = gm & (NS - 1);
        int h = gn >> 6, d = gn & 63;
        unsigned short hb = f2bfu(v);
        unsigned short lb = f2bfu(v - bfu2f(hb));
        size_t idx;
        if (MODE == 0)
          idx = (((size_t)b * NH + h) * NS + s) * NDK + d;
        else
          idx = (((size_t)b * NH + h) * NDV + d) * NS + s;
        reinterpret_cast<unsigned short*>(outp)[idx] = hb;
        outlo[idx] = lb;
      }
    }
  }
}

// ---------------- fused sparse attention (split precision) ----------------
// one workgroup = one (b,h) and 16 q rows. scores kept in LDS f32.
__global__ __launch_bounds__(256) void k_sparse_attn(
    const unsigned short* __restrict__ Qh, const unsigned short* __restrict__ Ql,
    const unsigned short* __restrict__ Kh, const unsigned short* __restrict__ Kl,
    const unsigned short* __restrict__ Vth, const unsigned short* __restrict__ Vtl,
    unsigned short* __restrict__ attn) {
  __shared__ __align__(16) float sc[16][2050];      // stride%8==2 -> <=2-way conflicts
  __shared__ __align__(16) unsigned short wlh[16][280];
  __shared__ __align__(16) unsigned short wll[16][280];
  __shared__ float rowcut[16], rowinv[16];

  const int tid = threadIdx.x;
  const int wave = tid >> 6, lane = tid & 63;
  const int lm = lane & 15, lg = lane >> 4;
  const int blk = blockIdx.x;
  const int qt = blk & (NS / 16 - 1);
  const int bh = blk >> 7;  // NS/16 == 128
  const int q0 = qt * 16;

  const size_t qoff = ((size_t)bh * NS + q0) * NDK;
  const unsigned short* Kph = Kh + (size_t)bh * NS * NDK;
  const unsigned short* Kpl = Kl + (size_t)bh * NS * NDK;
  const unsigned short* Vph = Vth + (size_t)bh * NDV * NS;
  const unsigned short* Vpl = Vtl + (size_t)bh * NDV * NS;

  // Q fragments (A operand), shared by all kv blocks
  short8 qh0 = *reinterpret_cast<const short8*>(Qh + qoff + lm * NDK + lg * 8);
  short8 qh1 = *reinterpret_cast<const short8*>(Qh + qoff + lm * NDK + 32 + lg * 8);
  short8 ql0 = *reinterpret_cast<const short8*>(Ql + qoff + lm * NDK + lg * 8);
  short8 ql1 = *reinterpret_cast<const short8*>(Ql + qoff + lm * NDK + 32 + lg * 8);

  // ---- QK^T: wave w covers kv columns [w*512, w*512+512) ----
  for (int t0 = wave * 512; t0 < wave * 512 + 512; t0 += 16) {
    f32x4 a = (f32x4){0.f, 0.f, 0.f, 0.f};
    size_t ko = (size_t)t0 * NDK;
    short8 bh0 = *reinterpret_cast<const short8*>(Kph + ko + lm * NDK + lg * 8);
    short8 bh1 = *reinterpret_cast<const short8*>(Kph + ko + lm * NDK + 32 + lg * 8);
    short8 bl0 = *reinterpret_cast<const short8*>(Kpl + ko + lm * NDK + lg * 8);
    short8 bl1 = *reinterpret_cast<const short8*>(Kpl + ko + lm * NDK + 32 + lg * 8);
    a = __builtin_amdgcn_mfma_f32_16x16x32_bf16(qh0, bh0, a, 0, 0, 0);
    a = __builtin_amdgcn_mfma_f32_16x16x32_bf16(qh1, bh1, a, 0, 0, 0);
    a = __builtin_amdgcn_mfma_f32_16x16x32_bf16(qh0, bl0, a, 0, 0, 0);
    a = __builtin_amdgcn_mfma_f32_16x16x32_bf16(qh1, bl1, a, 0, 0, 0);
    a = __builtin_amdgcn_mfma_f32_16x16x32_bf16(ql0, bh0, a, 0, 0, 0);
    a = __builtin_amdgcn_mfma_f32_16x16x32_bf16(ql1, bh1, a, 0, 0, 0);
#pragma unroll
    for (int r = 0; r < 4; r++)
      sc[lg * 4 + r][t0 + lm] = a[r] * 0.125f;  // 1/sqrt(64)
  }
  __syncthreads();

  // ---- softmax + iterative sparsification (closed form), wave owns rows 4w..4w+3 ----
  // Dd tracks cumulative product D0*D1'*...*D(t-1)'; cutE_t = thr_t*Dd*E;
  // Dd update: Dd <- Ssum/E + eps*Dd  ==  Dd_old*(S_t + eps). Exactly matches ref.
  float thr[3] = {1.0f / 2048.0f, 1.0f / (0.6f * 2048.0f), 1.0f / (0.36f * 2048.0f)};
  for (int rr = 0; rr < 4; rr++) {
    int row = wave * 4 + rr;
    float m = -1e30f;
    for (int i = lane; i < NS; i += 64) m = fmaxf(m, sc[row][i]);
    for (int s = 32; s > 0; s >>= 1) m = fmaxf(m, __shfl_xor(m, s));
    float E = 0.f;
    for (int i = lane; i < NS; i += 64) {
      float e = expf(sc[row][i] - m);
      sc[row][i] = e;  // overwrite scores with exp values
      E += e;
    }
    for (int s = 32; s > 0; s >>= 1) E += __shfl_xor(E, s);
    float Dd = 1.0f, cutE = 0.f;
#pragma unroll
    for (int t = 0; t < 3; t++) {
      cutE = fmaxf(cutE, thr[t] * Dd * E);
      float Ssum = 0.f;
      for (int i = lane; i < NS; i += 64) {
        float e = sc[row][i];
        if (e >= cutE) Ssum += e;
      }
      for (int s = 32; s > 0; s >>= 1) Ssum += __shfl_xor(Ssum, s);
      Dd = Ssum / E + 1e-9f * Dd;
    }
    if (lane == 0) {
      rowcut[row] = cutE;
      rowinv[row] = 1.0f / (E * Dd);  // final w = e * inv on kept set
    }
  }
  __syncthreads();

  // ---- PV: out(16 x 64) ; wave w owns dv columns [16w,16w+16). K blocked by 256. ----
  f32x4 pacc = (f32x4){0.f, 0.f, 0.f, 0.f};
  for (int kb = 0; kb < 8; kb++) {
    if (kb) __syncthreads();  // previous block's MFMA reads of wl done
    {
      int row = tid & 15, ch = tid >> 4;
      float cut = rowcut[row], inv = rowinv[row];
      int cbase = kb * 256 + ch * 16;
#pragma unroll
      for (int j = 0; j < 16; j++) {
        float e = sc[row][cbase + j];
        if (e >= cut) {
          float w = e * inv;
          unsigned short h = f2bfu(w);
          wlh[row][ch * 16 + j] = h;
          wll[row][ch * 16 + j] = f2bfu(w - bfu2f(h));
        } else {
          wlh[row][ch * 16 + j] = 0;
          wll[row][ch * 16 + j] = 0;
        }
      }
    }
    __syncthreads();
#pragma unroll
    for (int ks = 0; ks < 8; ks++) {
      short8 ah = *reinterpret_cast<const short8*>(&wlh[lm][ks * 32 + lg * 8]);
      short8 al = *reinterpret_cast<const short8*>(&wll[lm][ks * 32 + lg * 8]);
      size_t vo = (size_t)(wave * 16 + lm) * NS + kb * 256 + ks * 32 + lg * 8;
      short8 bh_ = *reinterpret_cast<const short8*>(Vph + vo);
      short8 bl_ = *reinterpret_cast<const short8*>(Vpl + vo);
      pacc = __builtin_amdgcn_mfma_f32_16x16x32_bf16(ah, bh_, pacc, 0, 0, 0);
      pacc = __builtin_amdgcn_mfma_f32_16x16x32_bf16(ah, bl_, pacc, 0, 0, 0);
      pacc = __builtin_amdgcn_mfma_f32_16x16x32_bf16(al, bh_, pacc, 0, 0, 0);
    }
  }

  // write attn_cat [b*NS+s][1536]: hi at col c and c+512, lo at c+1024
  int b = bh >> 3, h = bh & 7;
#pragma unroll
  for (int r = 0; r < 4; r++) {
    int s = q0 + lg * 4 + r;
    int c = h * 64 + wave * 16 + lm;
    float v = pacc[r];
    unsigned short hb = f2bfu(v);
    unsigned short lb = f2bfu(v - bfu2f(hb));
    size_t base = ((size_t)b * NS + s) * 1536;
    attn[base + c] = hb;
    attn[base + c + 512] = hb;
    attn[base + c + 1024] = lb;
  }
}

// ---------------- launch ----------------

extern "C" void kernel_launch(void* const* d_in, const int* in_sizes, int n_in,
                              void* d_out, int out_size, void* d_ws, size_t ws_size,
                              hipStream_t stream) {
  const float* x  = (const float*)d_in[0];
  const float* Wq = (const float*)d_in[1];
  const float* bq = (const float*)d_in[2];
  const float* Wk = (const float*)d_in[3];
  const float* bk = (const float*)d_in[4];
  const float* Wv = (const float*)d_in[5];
  const float* bv = (const float*)d_in[6];
  const float* Wo = (const float*)d_in[7];
  const float* bo = (const float*)d_in[8];

  char* ws = (char*)d_ws;
  size_t off = 0;
  auto alloc = [&](size_t bytes) {
    char* p = ws + off;
    off += (bytes + 255) & ~(size_t)255;
    return p;
  };
  const int M = NB * NS;  // 8192
  unsigned short* xcat = (unsigned short*)alloc((size_t)M * 1536 * 2);  // reused as attn_cat
  unsigned short* wqC  = (unsigned short*)alloc((size_t)512 * 1536 * 2);
  unsigned short* wkC  = (unsigned short*)alloc((size_t)512 * 1536 * 2);
  unsigned short* wvC  = (unsigned short*)alloc((size_t)512 * 1536 * 2);
  unsigned short* woC  = (unsigned short*)alloc((size_t)512 * 1536 * 2);
  unsigned short* Qhi  = (unsigned short*)alloc((size_t)M * 512 * 2);
  unsigned short* Qlo  = (unsigned short*)alloc((size_t)M * 512 * 2);
  unsigned short* Khi  = (unsigned short*)alloc((size_t)M * 512 * 2);
  unsigned short* Klo  = (unsigned short*)alloc((size_t)M * 512 * 2);
  unsigned short* Vthi = (unsigned short*)alloc((size_t)M * 512 * 2);
  unsigned short* Vtlo = (unsigned short*)alloc((size_t)M * 512 * 2);
  unsigned short* attn = xcat;  // alias: xcat dead after V projection

  k_make_xcat<<<(M * 512 / 4 + 255) / 256, 256, 0, stream>>>(x, xcat, M * 512 / 4);

  dim3 tg(16, 16), tb(32, 8);
  k_transpose_split<<<tg, tb, 0, stream>>>(Wq, wqC, ND, NH * NDK);
  k_transpose_split<<<tg, tb, 0, stream>>>(Wk, wkC, ND, NH * NDK);
  k_transpose_split<<<tg, tb, 0, stream>>>(Wv, wvC, ND, NH * NDV);
  k_transpose_split<<<tg, tb, 0, stream>>>(Wo, woC, NH * NDV, ND);

  dim3 gg(512 / 64, M / 64);
  k_gemm_nt<0><<<gg, 256, 0, stream>>>(xcat, wqC, bq, Qhi, Qlo, M, 512, 1536);
  k_gemm_nt<0><<<gg, 256, 0, stream>>>(xcat, wkC, bk, Khi, Klo, M, 512, 1536);
  k_gemm_nt<2><<<gg, 256, 0, stream>>>(xcat, wvC, bv, Vthi, Vtlo, M, 512, 1536);

  k_sparse_attn<<<NB * NH * (NS / 16), 256, 0, stream>>>(Qhi, Qlo, Khi, Klo, Vthi, Vtlo, attn);

  k_gemm_nt<3><<<gg, 256, 0, stream>>>(attn, woC, bo, d_out, nullptr, M, 512, 1536);
}

// Round 4
// 976.125 us; speedup vs baseline: 1.6749x; 1.6749x over previous
//
#include <hip/hip_runtime.h>
#include <hip/hip_bf16.h>
#include <math.h>

#define NB 4
#define NS 2048
#define ND 512
#define NH 8
#define NDK 64
#define NDV 64

typedef __attribute__((ext_vector_type(8))) short short8;
typedef __attribute__((ext_vector_type(4))) float f32x4;

__device__ __forceinline__ unsigned short f2bfu(float f) {
  // round-to-nearest-even bf16 (inputs finite)
  unsigned int u = __builtin_bit_cast(unsigned int, f);
  unsigned int rounding = 0x7fffu + ((u >> 16) & 1u);
  return (unsigned short)((u + rounding) >> 16);
}
__device__ __forceinline__ float bfu2f(unsigned short u) {
  return __builtin_bit_cast(float, (unsigned int)u << 16);
}

// ---------------- prep kernels ----------------

// x [M][512] f32 -> xcat [M][1536] bf16 = [xhi | xhi | xlo]
__global__ void k_make_xcat(const float* __restrict__ in, unsigned short* __restrict__ out,
                            int n4) {
  int i = blockIdx.x * 256 + threadIdx.x;
  if (i >= n4) return;
  int row = i >> 7, col = (i & 127) * 4;  // 512/4 = 128 chunks per row
  float4 f = reinterpret_cast<const float4*>(in)[i];
  ushort4 h, l;
  h.x = f2bfu(f.x); h.y = f2bfu(f.y); h.z = f2bfu(f.z); h.w = f2bfu(f.w);
  l.x = f2bfu(f.x - bfu2f(h.x)); l.y = f2bfu(f.y - bfu2f(h.y));
  l.z = f2bfu(f.z - bfu2f(h.z)); l.w = f2bfu(f.w - bfu2f(h.w));
  ushort4* o = reinterpret_cast<ushort4*>(out + (size_t)row * 1536);
  o[col / 4] = h;
  o[(col + 512) / 4] = h;
  o[(col + 1024) / 4] = l;
}

// W [R][C] f32 -> Wcat [C][3R] bf16 rows = [Whi^T | Wlo^T | Whi^T]
__global__ void k_transpose_split(const float* __restrict__ src, unsigned short* __restrict__ dst,
                                  int R, int C) {
  __shared__ float t[32][33];
  int bx = blockIdx.x * 32, by = blockIdx.y * 32;
  int tx = threadIdx.x, ty = threadIdx.y;
  for (int i = 0; i < 32; i += 8)
    t[ty + i][tx] = src[(size_t)(by + ty + i) * C + bx + tx];
  __syncthreads();
  for (int i = 0; i < 32; i += 8) {
    float f = t[tx][ty + i];
    unsigned short h = f2bfu(f);
    unsigned short l = f2bfu(f - bfu2f(h));
    size_t base = (size_t)(bx + ty + i) * (3 * R) + by + tx;
    dst[base] = h;
    dst[base + R] = l;
    dst[base + 2 * R] = h;
  }
}

// ---------------- NT MFMA GEMM: C = A * Bt^T + bias ----------------
// A [M][K] bf16 row-major, Bt [N][K] bf16 row-major. 64x64 tile, 256 threads.
// MODE 0: out -> hi/lo [b][h][s][dk] bf16   MODE 2: out -> hi/lo V^T [b][h][dv][s] bf16
// MODE 3: out -> f32 [M][ND]
template <int MODE>
__global__ __launch_bounds__(256) void k_gemm_nt(
    const unsigned short* __restrict__ A, const unsigned short* __restrict__ Bt,
    const float* __restrict__ bias, void* __restrict__ outp, unsigned short* __restrict__ outlo,
    int M, int N, int K) {
  __shared__ __align__(16) unsigned short As[64][88];
  __shared__ __align__(16) unsigned short Bs[64][88];
  const int tid = threadIdx.x;
  const int m0 = blockIdx.y * 64;
  const int n0 = blockIdx.x * 64;
  const int wave = tid >> 6, lane = tid & 63;
  const int lm = lane & 15, lg = lane >> 4;

  f32x4 acc[4];
  for (int n = 0; n < 4; n++) acc[n] = (f32x4){0.f, 0.f, 0.f, 0.f};

  for (int k0 = 0; k0 < K; k0 += 64) {
    for (int it = 0; it < 2; it++) {
      int c = tid + it * 256;            // 512 chunks of 8 elems = 64x64 tile
      int row = c >> 3, col = (c & 7) * 8;
      *reinterpret_cast<short8*>(&As[row][col]) =
          *reinterpret_cast<const short8*>(A + (size_t)(m0 + row) * K + k0 + col);
      *reinterpret_cast<short8*>(&Bs[row][col]) =
          *reinterpret_cast<const short8*>(Bt + (size_t)(n0 + row) * K + k0 + col);
    }
    __syncthreads();
#pragma unroll
    for (int ks = 0; ks < 2; ks++) {
      short8 a = *reinterpret_cast<const short8*>(&As[wave * 16 + lm][ks * 32 + lg * 8]);
#pragma unroll
      for (int n = 0; n < 4; n++) {
        short8 b = *reinterpret_cast<const short8*>(&Bs[n * 16 + lm][ks * 32 + lg * 8]);
        acc[n] = __builtin_amdgcn_mfma_f32_16x16x32_bf16(a, b, acc[n], 0, 0, 0);
      }
    }
    __syncthreads();
  }

#pragma unroll
  for (int n = 0; n < 4; n++) {
    int gn = n0 + n * 16 + lm;
    float bv = bias[gn];
#pragma unroll
    for (int r = 0; r < 4; r++) {
      int gm = m0 + wave * 16 + lg * 4 + r;
      float v = acc[n][r] + bv;
      if (MODE == 3) {
        reinterpret_cast<float*>(outp)[(size_t)gm * ND + gn] = v;
      } else {
        int b = gm >> 11, s = gm & (NS - 1);
        int h = gn >> 6, d = gn & 63;
        unsigned short hb = f2bfu(v);
        unsigned short lb = f2bfu(v - bfu2f(hb));
        size_t idx;
        if (MODE == 0)
          idx = (((size_t)b * NH + h) * NS + s) * NDK + d;
        else
          idx = (((size_t)b * NH + h) * NDV + d) * NS + s;
        reinterpret_cast<unsigned short*>(outp)[idx] = hb;
        outlo[idx] = lb;
      }
    }
  }
}

// ---------------- fused sparse attention (split precision, 16 waves) ----------------
// one workgroup = one (b,h) + 16 q rows; 1024 threads (16 waves), 1 block/CU.
__global__ __launch_bounds__(1024) void k_sparse_attn(
    const unsigned short* __restrict__ Qh, const unsigned short* __restrict__ Ql,
    const unsigned short* __restrict__ Kh, const unsigned short* __restrict__ Kl,
    const unsigned short* __restrict__ Vth, const unsigned short* __restrict__ Vtl,
    unsigned short* __restrict__ attn) {
  __shared__ __align__(16) float sc[16][2052];     // row stride %32 == 4 -> <=2-way on b128
  __shared__ __align__(16) float red[4][4][16][16];  // [kblk][dvblk][q][dv]
  __shared__ float rowcut[16], rowinv[16];

  const int tid = threadIdx.x;
  const int wave = tid >> 6, lane = tid & 63;
  const int lm = lane & 15, lg = lane >> 4;

  // bijective XCD swizzle: 4096 wgs -> XCD x gets logical ids [x*512, x*512+512)
  // so concurrently-resident blocks on an XCD share one (b,h)'s K/V (~2.5MB <= 4MB L2)
  const int orig = blockIdx.x;
  const int blk = (orig & 7) * 512 + (orig >> 3);
  const int qt = blk & (NS / 16 - 1);
  const int bh = blk >> 7;  // NS/16 == 128
  const int q0 = qt * 16;

  const size_t qoff = ((size_t)bh * NS + q0) * NDK;
  const unsigned short* Kph = Kh + (size_t)bh * NS * NDK;
  const unsigned short* Kpl = Kl + (size_t)bh * NS * NDK;
  const unsigned short* Vph = Vth + (size_t)bh * NDV * NS;
  const unsigned short* Vpl = Vtl + (size_t)bh * NDV * NS;

  // ---- QK^T: wave w covers kv columns [w*128, w*128+128) ----
  {
    short8 qh0 = *reinterpret_cast<const short8*>(Qh + qoff + lm * NDK + lg * 8);
    short8 qh1 = *reinterpret_cast<const short8*>(Qh + qoff + lm * NDK + 32 + lg * 8);
    short8 ql0 = *reinterpret_cast<const short8*>(Ql + qoff + lm * NDK + lg * 8);
    short8 ql1 = *reinterpret_cast<const short8*>(Ql + qoff + lm * NDK + 32 + lg * 8);
#pragma unroll
    for (int it = 0; it < 8; it++) {
      int t0 = wave * 128 + it * 16;
      f32x4 a = (f32x4){0.f, 0.f, 0.f, 0.f};
      size_t ko = (size_t)t0 * NDK;
      short8 bh0 = *reinterpret_cast<const short8*>(Kph + ko + lm * NDK + lg * 8);
      short8 bh1 = *reinterpret_cast<const short8*>(Kph + ko + lm * NDK + 32 + lg * 8);
      short8 bl0 = *reinterpret_cast<const short8*>(Kpl + ko + lm * NDK + lg * 8);
      short8 bl1 = *reinterpret_cast<const short8*>(Kpl + ko + lm * NDK + 32 + lg * 8);
      a = __builtin_amdgcn_mfma_f32_16x16x32_bf16(qh0, bh0, a, 0, 0, 0);
      a = __builtin_amdgcn_mfma_f32_16x16x32_bf16(qh1, bh1, a, 0, 0, 0);
      a = __builtin_amdgcn_mfma_f32_16x16x32_bf16(qh0, bl0, a, 0, 0, 0);
      a = __builtin_amdgcn_mfma_f32_16x16x32_bf16(qh1, bl1, a, 0, 0, 0);
      a = __builtin_amdgcn_mfma_f32_16x16x32_bf16(ql0, bh0, a, 0, 0, 0);
      a = __builtin_amdgcn_mfma_f32_16x16x32_bf16(ql1, bh1, a, 0, 0, 0);
#pragma unroll
      for (int r = 0; r < 4; r++)
        sc[lg * 4 + r][t0 + lm] = a[r] * 0.125f;  // 1/sqrt(64)
    }
  }
  __syncthreads();

  // ---- softmax + sparsification (closed form): one row per wave, fully parallel ----
  // Dd tracks cumulative product D0*D1'*...; cutE_t = thr_t*Dd*E; Dd <- Ssum/E + eps*Dd.
  {
    const float thr[3] = {1.0f / 2048.0f, 1.0f / (0.6f * 2048.0f), 1.0f / (0.36f * 2048.0f)};
    const int row = wave;
    float m = -1e30f;
    for (int i = lane; i < NS; i += 64) m = fmaxf(m, sc[row][i]);
    for (int s = 32; s > 0; s >>= 1) m = fmaxf(m, __shfl_xor(m, s));
    float E = 0.f;
    for (int i = lane; i < NS; i += 64) {
      float e = __expf(sc[row][i] - m);
      sc[row][i] = e;  // overwrite scores with exp values
      E += e;
    }
    for (int s = 32; s > 0; s >>= 1) E += __shfl_xor(E, s);
    float Dd = 1.0f, cutE = 0.f;
#pragma unroll
    for (int t = 0; t < 3; t++) {
      cutE = fmaxf(cutE, thr[t] * Dd * E);
      float Ssum = 0.f;
      for (int i = lane; i < NS; i += 64) {
        float e = sc[row][i];
        if (e >= cutE) Ssum += e;
      }
      for (int s = 32; s > 0; s >>= 1) Ssum += __shfl_xor(Ssum, s);
      Dd = Ssum / E + 1e-9f * Dd;
    }
    if (lane == 0) {
      rowcut[row] = cutE;
      rowinv[row] = 1.0f / (E * Dd);  // final w = e * inv on kept set
    }
  }
  __syncthreads();

  // ---- PV: wave (d = wave&3) owns dv cols [16d,16d+16), (kk = wave>>2) k-range 512 ----
  {
    const int d = wave & 3;
    const int kk = wave >> 2;
    const float cut = rowcut[lm], inv = rowinv[lm];
    const unsigned short* vph = Vph + (size_t)(d * 16 + lm) * NS + kk * 512;
    const unsigned short* vpl = Vpl + (size_t)(d * 16 + lm) * NS + kk * 512;
    f32x4 pacc = (f32x4){0.f, 0.f, 0.f, 0.f};
#pragma unroll
    for (int ks = 0; ks < 16; ks++) {
      int c = kk * 512 + ks * 32 + lg * 8;
      f32x4 e0 = *reinterpret_cast<const f32x4*>(&sc[lm][c]);
      f32x4 e1 = *reinterpret_cast<const f32x4*>(&sc[lm][c + 4]);
      short8 ah, al;
#pragma unroll
      for (int j = 0; j < 4; j++) {
        float w0 = (e0[j] >= cut) ? e0[j] * inv : 0.f;
        unsigned short h0 = f2bfu(w0);
        ah[j] = (short)h0; al[j] = (short)f2bfu(w0 - bfu2f(h0));
        float w1 = (e1[j] >= cut) ? e1[j] * inv : 0.f;
        unsigned short h1 = f2bfu(w1);
        ah[4 + j] = (short)h1; al[4 + j] = (short)f2bfu(w1 - bfu2f(h1));
      }
      short8 vh = *reinterpret_cast<const short8*>(vph + ks * 32 + lg * 8);
      short8 vl = *reinterpret_cast<const short8*>(vpl + ks * 32 + lg * 8);
      pacc = __builtin_amdgcn_mfma_f32_16x16x32_bf16(ah, vh, pacc, 0, 0, 0);
      pacc = __builtin_amdgcn_mfma_f32_16x16x32_bf16(ah, vl, pacc, 0, 0, 0);
      pacc = __builtin_amdgcn_mfma_f32_16x16x32_bf16(al, vh, pacc, 0, 0, 0);
    }
#pragma unroll
    for (int r = 0; r < 4; r++) red[kk][d][lg * 4 + r][lm] = pacc[r];
  }
  __syncthreads();

  // ---- reduce k-partials and store; attn_cat [b*NS+s][1536]: hi at c, c+512; lo at c+1024
  if (wave < 4) {
    const int d = wave;
    const int b = bh >> 3, h = bh & 7;
#pragma unroll
    for (int r = 0; r < 4; r++) {
      int q = lg * 4 + r;
      float v = red[0][d][q][lm] + red[1][d][q][lm] + red[2][d][q][lm] + red[3][d][q][lm];
      int s = q0 + q;
      int c = h * 64 + d * 16 + lm;
      unsigned short hb = f2bfu(v);
      unsigned short lb = f2bfu(v - bfu2f(hb));
      size_t base = ((size_t)b * NS + s) * 1536;
      attn[base + c] = hb;
      attn[base + c + 512] = hb;
      attn[base + c + 1024] = lb;
    }
  }
}

// ---------------- launch ----------------

extern "C" void kernel_launch(void* const* d_in, const int* in_sizes, int n_in,
                              void* d_out, int out_size, void* d_ws, size_t ws_size,
                              hipStream_t stream) {
  const float* x  = (const float*)d_in[0];
  const float* Wq = (const float*)d_in[1];
  const float* bq = (const float*)d_in[2];
  const float* Wk = (const float*)d_in[3];
  const float* bk = (const float*)d_in[4];
  const float* Wv = (const float*)d_in[5];
  const float* bv = (const float*)d_in[6];
  const float* Wo = (const float*)d_in[7];
  const float* bo = (const float*)d_in[8];

  char* ws = (char*)d_ws;
  size_t off = 0;
  auto alloc = [&](size_t bytes) {
    char* p = ws + off;
    off += (bytes + 255) & ~(size_t)255;
    return p;
  };
  const int M = NB * NS;  // 8192
  unsigned short* xcat = (unsigned short*)alloc((size_t)M * 1536 * 2);  // reused as attn_cat
  unsigned short* wqC  = (unsigned short*)alloc((size_t)512 * 1536 * 2);
  unsigned short* wkC  = (unsigned short*)alloc((size_t)512 * 1536 * 2);
  unsigned short* wvC  = (unsigned short*)alloc((size_t)512 * 1536 * 2);
  unsigned short* woC  = (unsigned short*)alloc((size_t)512 * 1536 * 2);
  unsigned short* Qhi  = (unsigned short*)alloc((size_t)M * 512 * 2);
  unsigned short* Qlo  = (unsigned short*)alloc((size_t)M * 512 * 2);
  unsigned short* Khi  = (unsigned short*)alloc((size_t)M * 512 * 2);
  unsigned short* Klo  = (unsigned short*)alloc((size_t)M * 512 * 2);
  unsigned short* Vthi = (unsigned short*)alloc((size_t)M * 512 * 2);
  unsigned short* Vtlo = (unsigned short*)alloc((size_t)M * 512 * 2);
  unsigned short* attn = xcat;  // alias: xcat dead after V projection

  k_make_xcat<<<(M * 512 / 4 + 255) / 256, 256, 0, stream>>>(x, xcat, M * 512 / 4);

  dim3 tg(16, 16), tb(32, 8);
  k_transpose_split<<<tg, tb, 0, stream>>>(Wq, wqC, ND, NH * NDK);
  k_transpose_split<<<tg, tb, 0, stream>>>(Wk, wkC, ND, NH * NDK);
  k_transpose_split<<<tg, tb, 0, stream>>>(Wv, wvC, ND, NH * NDV);
  k_transpose_split<<<tg, tb, 0, stream>>>(Wo, woC, NH * NDV, ND);

  dim3 gg(512 / 64, M / 64);
  k_gemm_nt<0><<<gg, 256, 0, stream>>>(xcat, wqC, bq, Qhi, Qlo, M, 512, 1536);
  k_gemm_nt<0><<<gg, 256, 0, stream>>>(xcat, wkC, bk, Khi, Klo, M, 512, 1536);
  k_gemm_nt<2><<<gg, 256, 0, stream>>>(xcat, wvC, bv, Vthi, Vtlo, M, 512, 1536);

  k_sparse_attn<<<NB * NH * (NS / 16), 1024, 0, stream>>>(Qhi, Qlo, Khi, Klo, Vthi, Vtlo, attn);

  k_gemm_nt<3><<<gg, 256, 0, stream>>>(attn, woC, bo, d_out, nullptr, M, 512, 1536);
}

// Round 6
// 899.596 us; speedup vs baseline: 1.8174x; 1.0851x over previous
//
#include <hip/hip_runtime.h>
#include <hip/hip_bf16.h>
#include <math.h>

#define NB 4
#define NS 2048
#define ND 512
#define NH 8
#define NDK 64
#define NDV 64

typedef __attribute__((ext_vector_type(8))) short short8;
typedef __attribute__((ext_vector_type(4))) float f32x4;

__device__ __forceinline__ unsigned short f2bfu(float f) {
  // round-to-nearest-even bf16 (inputs finite)
  unsigned int u = __builtin_bit_cast(unsigned int, f);
  unsigned int rounding = 0x7fffu + ((u >> 16) & 1u);
  return (unsigned short)((u + rounding) >> 16);
}
__device__ __forceinline__ float bfu2f(unsigned short u) {
  return __builtin_bit_cast(float, (unsigned int)u << 16);
}

// ---------------- prep kernels ----------------

// x [M][512] f32 -> xcat [M][1536] bf16 = [xhi | xhi | xlo]
__global__ void k_make_xcat(const float* __restrict__ in, unsigned short* __restrict__ out,
                            int n4) {
  int i = blockIdx.x * 256 + threadIdx.x;
  if (i >= n4) return;
  int row = i >> 7, col = (i & 127) * 4;  // 512/4 = 128 chunks per row
  float4 f = reinterpret_cast<const float4*>(in)[i];
  ushort4 h, l;
  h.x = f2bfu(f.x); h.y = f2bfu(f.y); h.z = f2bfu(f.z); h.w = f2bfu(f.w);
  l.x = f2bfu(f.x - bfu2f(h.x)); l.y = f2bfu(f.y - bfu2f(h.y));
  l.z = f2bfu(f.z - bfu2f(h.z)); l.w = f2bfu(f.w - bfu2f(h.w));
  ushort4* o = reinterpret_cast<ushort4*>(out + (size_t)row * 1536);
  o[col / 4] = h;
  o[(col + 512) / 4] = h;
  o[(col + 1024) / 4] = l;
}

// W [R][C] f32 -> Wcat [C][3R] bf16 rows = [Whi^T | Wlo^T | Whi^T]
__global__ void k_transpose_split(const float* __restrict__ src, unsigned short* __restrict__ dst,
                                  int R, int C) {
  __shared__ float t[32][33];
  int bx = blockIdx.x * 32, by = blockIdx.y * 32;
  int tx = threadIdx.x, ty = threadIdx.y;
  for (int i = 0; i < 32; i += 8)
    t[ty + i][tx] = src[(size_t)(by + ty + i) * C + bx + tx];
  __syncthreads();
  for (int i = 0; i < 32; i += 8) {
    float f = t[tx][ty + i];
    unsigned short h = f2bfu(f);
    unsigned short l = f2bfu(f - bfu2f(h));
    size_t base = (size_t)(bx + ty + i) * (3 * R) + by + tx;
    dst[base] = h;
    dst[base + R] = l;
    dst[base + 2 * R] = h;
  }
}

// ---------------- NT MFMA GEMM: C = A * Bt^T + bias ----------------
// A [M][K] bf16 row-major, Bt [N][K] bf16 row-major. 64x64 tile, 256 threads.
// MODE 0: out -> hi/lo [b][h][s][dk] bf16   MODE 2: out -> hi/lo V^T [b][h][dv][s] bf16
// MODE 3: out -> f32 [M][ND]
template <int MODE>
__global__ __launch_bounds__(256) void k_gemm_nt(
    const unsigned short* __restrict__ A, const unsigned short* __restrict__ Bt,
    const float* __restrict__ bias, void* __restrict__ outp, unsigned short* __restrict__ outlo,
    int M, int N, int K) {
  __shared__ __align__(16) unsigned short As[64][88];
  __shared__ __align__(16) unsigned short Bs[64][88];
  const int tid = threadIdx.x;
  const int m0 = blockIdx.y * 64;
  const int n0 = blockIdx.x * 64;
  const int wave = tid >> 6, lane = tid & 63;
  const int lm = lane & 15, lg = lane >> 4;

  f32x4 acc[4];
  for (int n = 0; n < 4; n++) acc[n] = (f32x4){0.f, 0.f, 0.f, 0.f};

  for (int k0 = 0; k0 < K; k0 += 64) {
    for (int it = 0; it < 2; it++) {
      int c = tid + it * 256;            // 512 chunks of 8 elems = 64x64 tile
      int row = c >> 3, col = (c & 7) * 8;
      *reinterpret_cast<short8*>(&As[row][col]) =
          *reinterpret_cast<const short8*>(A + (size_t)(m0 + row) * K + k0 + col);
      *reinterpret_cast<short8*>(&Bs[row][col]) =
          *reinterpret_cast<const short8*>(Bt + (size_t)(n0 + row) * K + k0 + col);
    }
    __syncthreads();
#pragma unroll
    for (int ks = 0; ks < 2; ks++) {
      short8 a = *reinterpret_cast<const short8*>(&As[wave * 16 + lm][ks * 32 + lg * 8]);
#pragma unroll
      for (int n = 0; n < 4; n++) {
        short8 b = *reinterpret_cast<const short8*>(&Bs[n * 16 + lm][ks * 32 + lg * 8]);
        acc[n] = __builtin_amdgcn_mfma_f32_16x16x32_bf16(a, b, acc[n], 0, 0, 0);
      }
    }
    __syncthreads();
  }

#pragma unroll
  for (int n = 0; n < 4; n++) {
    int gn = n0 + n * 16 + lm;
    float bv = bias[gn];
#pragma unroll
    for (int r = 0; r < 4; r++) {
      int gm = m0 + wave * 16 + lg * 4 + r;
      float v = acc[n][r] + bv;
      if (MODE == 3) {
        reinterpret_cast<float*>(outp)[(size_t)gm * ND + gn] = v;
      } else {
        int b = gm >> 11, s = gm & (NS - 1);
        int h = gn >> 6, d = gn & 63;
        unsigned short hb = f2bfu(v);
        unsigned short lb = f2bfu(v - bfu2f(hb));
        size_t idx;
        if (MODE == 0)
          idx = (((size_t)b * NH + h) * NS + s) * NDK + d;
        else
          idx = (((size_t)b * NH + h) * NDV + d) * NS + s;
        reinterpret_cast<unsigned short*>(outp)[idx] = hb;
        outlo[idx] = lb;
      }
    }
  }
}

// ---------------- fused sparse attention (split precision, 16 waves) ----------------
// one workgroup = one (b,h) + 16 q rows; 1024 threads (16 waves), 1 block/CU.
// sc row layout over time: f32 scores/exp [0,8208) -> after softmax, packed planes:
//   w_hi bf16 at bytes [0,4096), w_lo bf16 at bytes [4096,8192).
__global__ __launch_bounds__(1024) void k_sparse_attn(
    const unsigned short* __restrict__ Qh, const unsigned short* __restrict__ Ql,
    const unsigned short* __restrict__ Kh, const unsigned short* __restrict__ Kl,
    const unsigned short* __restrict__ Vth, const unsigned short* __restrict__ Vtl,
    unsigned short* __restrict__ attn) {
  __shared__ __align__(16) float sc[16][2052];       // stride%32==4 dwords -> uniform banks
  __shared__ __align__(16) float red[4][4][16][16];  // [kblk][dvblk][q][dv]

  const int tid = threadIdx.x;
  const int wave = tid >> 6, lane = tid & 63;
  const int lm = lane & 15, lg = lane >> 4;

  // bijective XCD swizzle: 4096 wgs -> XCD x gets logical ids [x*512, x*512+512)
  const int orig = blockIdx.x;
  const int blk = (orig & 7) * 512 + (orig >> 3);
  const int qt = blk & (NS / 16 - 1);
  const int bh = blk >> 7;  // NS/16 == 128
  const int q0 = qt * 16;

  const size_t qoff = ((size_t)bh * NS + q0) * NDK;
  const unsigned short* Kph = Kh + (size_t)bh * NS * NDK;
  const unsigned short* Kpl = Kl + (size_t)bh * NS * NDK;
  const unsigned short* Vph = Vth + (size_t)bh * NDV * NS;
  const unsigned short* Vpl = Vtl + (size_t)bh * NDV * NS;

  // ---- QK^T (swapped operands: mfma(K,Q) -> reg-dim = kv, lane-dim = q) ----
  // wave w covers kv [w*128, w*128+128); per lane one ds_write_b128 per 16-kv tile.
  {
    short8 qh0 = *reinterpret_cast<const short8*>(Qh + qoff + lm * NDK + lg * 8);
    short8 qh1 = *reinterpret_cast<const short8*>(Qh + qoff + lm * NDK + 32 + lg * 8);
    short8 ql0 = *reinterpret_cast<const short8*>(Ql + qoff + lm * NDK + lg * 8);
    short8 ql1 = *reinterpret_cast<const short8*>(Ql + qoff + lm * NDK + 32 + lg * 8);
#pragma unroll
    for (int it = 0; it < 8; it += 2) {
      int t0a = wave * 128 + it * 16;
      int t0b = t0a + 16;
      size_t koa = (size_t)t0a * NDK, kob = (size_t)t0b * NDK;
      // issue all 8 K loads for both sub-iterations before any MFMA
      short8 ah0 = *reinterpret_cast<const short8*>(Kph + koa + lm * NDK + lg * 8);
      short8 ah1 = *reinterpret_cast<const short8*>(Kph + koa + lm * NDK + 32 + lg * 8);
      short8 al0 = *reinterpret_cast<const short8*>(Kpl + koa + lm * NDK + lg * 8);
      short8 al1 = *reinterpret_cast<const short8*>(Kpl + koa + lm * NDK + 32 + lg * 8);
      short8 bh0 = *reinterpret_cast<const short8*>(Kph + kob + lm * NDK + lg * 8);
      short8 bh1 = *reinterpret_cast<const short8*>(Kph + kob + lm * NDK + 32 + lg * 8);
      short8 bl0 = *reinterpret_cast<const short8*>(Kpl + kob + lm * NDK + lg * 8);
      short8 bl1 = *reinterpret_cast<const short8*>(Kpl + kob + lm * NDK + 32 + lg * 8);
      {
        f32x4 a0 = (f32x4){0.f, 0.f, 0.f, 0.f};
        f32x4 a1 = (f32x4){0.f, 0.f, 0.f, 0.f};
        a0 = __builtin_amdgcn_mfma_f32_16x16x32_bf16(ah0, qh0, a0, 0, 0, 0);
        a1 = __builtin_amdgcn_mfma_f32_16x16x32_bf16(ah1, qh1, a1, 0, 0, 0);
        a0 = __builtin_amdgcn_mfma_f32_16x16x32_bf16(al0, qh0, a0, 0, 0, 0);
        a1 = __builtin_amdgcn_mfma_f32_16x16x32_bf16(al1, qh1, a1, 0, 0, 0);
        a0 = __builtin_amdgcn_mfma_f32_16x16x32_bf16(ah0, ql0, a0, 0, 0, 0);
        a1 = __builtin_amdgcn_mfma_f32_16x16x32_bf16(ah1, ql1, a1, 0, 0, 0);
        f32x4 v = (a0 + a1) * 0.125f;  // 1/sqrt(64)
        *reinterpret_cast<f32x4*>(&sc[lm][t0a + lg * 4]) = v;
      }
      {
        f32x4 a0 = (f32x4){0.f, 0.f, 0.f, 0.f};
        f32x4 a1 = (f32x4){0.f, 0.f, 0.f, 0.f};
        a0 = __builtin_amdgcn_mfma_f32_16x16x32_bf16(bh0, qh0, a0, 0, 0, 0);
        a1 = __builtin_amdgcn_mfma_f32_16x16x32_bf16(bh1, qh1, a1, 0, 0, 0);
        a0 = __builtin_amdgcn_mfma_f32_16x16x32_bf16(bl0, qh0, a0, 0, 0, 0);
        a1 = __builtin_amdgcn_mfma_f32_16x16x32_bf16(bl1, qh1, a1, 0, 0, 0);
        a0 = __builtin_amdgcn_mfma_f32_16x16x32_bf16(bh0, ql0, a0, 0, 0, 0);
        a1 = __builtin_amdgcn_mfma_f32_16x16x32_bf16(bh1, ql1, a1, 0, 0, 0);
        f32x4 v = (a0 + a1) * 0.125f;
        *reinterpret_cast<f32x4*>(&sc[lm][t0b + lg * 4]) = v;
      }
    }
  }
  __syncthreads();

  // ---- softmax + sparsification + w-conversion, fully in registers; wave w owns row w ----
  // Dd tracks cumulative product; cutE_t = thr_t*Dd*E; Dd <- Ssum/E + eps*Dd.
  {
    const float thr[3] = {1.0f / 2048.0f, 1.0f / (0.6f * 2048.0f), 1.0f / (0.36f * 2048.0f)};
    char* rb = (char*)&sc[wave][0];
    f32x4 ev[8];
#pragma unroll
    for (int it = 0; it < 8; it++)
      ev[it] = *reinterpret_cast<const f32x4*>(rb + 4 * (it * 256 + lane * 4));
    float m = -1e30f;
#pragma unroll
    for (int it = 0; it < 8; it++)
      m = fmaxf(m, fmaxf(fmaxf(ev[it][0], ev[it][1]), fmaxf(ev[it][2], ev[it][3])));
    for (int s = 32; s > 0; s >>= 1) m = fmaxf(m, __shfl_xor(m, s));
    float E = 0.f;
#pragma unroll
    for (int it = 0; it < 8; it++) {
#pragma unroll
      for (int j = 0; j < 4; j++) {
        float e = __expf(ev[it][j] - m);
        ev[it][j] = e;
        E += e;
      }
    }
    for (int s = 32; s > 0; s >>= 1) E += __shfl_xor(E, s);
    float Dd = 1.0f, cut = 0.f;
#pragma unroll
    for (int t = 0; t < 3; t++) {
      cut = fmaxf(cut, thr[t] * Dd * E);
      float Ssum = 0.f;
#pragma unroll
      for (int it = 0; it < 8; it++) {
#pragma unroll
        for (int j = 0; j < 4; j++) Ssum += (ev[it][j] >= cut) ? ev[it][j] : 0.f;
      }
      for (int s = 32; s > 0; s >>= 1) Ssum += __shfl_xor(Ssum, s);
      Dd = Ssum / E + 1e-9f * Dd;
    }
    const float inv = 1.0f / (E * Dd);  // final w = e * inv on kept set
    // convert once: packed hi plane [0,4096), lo plane [4096,8192) within this row.
    // Safe in-place: this wave read its whole row into ev before any write; DS ops
    // complete in order within a wave.
#pragma unroll
    for (int it = 0; it < 8; it++) {
      ushort4 hv, lv;
#pragma unroll
      for (int j = 0; j < 4; j++) {
        float e = ev[it][j];
        float w = (e >= cut) ? e * inv : 0.f;
        unsigned short h = f2bfu(w);
        (&hv.x)[j] = h;
        (&lv.x)[j] = f2bfu(w - bfu2f(h));
      }
      int c = it * 256 + lane * 4;
      *reinterpret_cast<ushort4*>(rb + 2 * c) = hv;
      *reinterpret_cast<ushort4*>(rb + 4096 + 2 * c) = lv;
    }
  }
  __syncthreads();

  // ---- PV: wave (d = wave&3) owns dv cols [16d,16d+16), (kk = wave>>2) k-range 512 ----
  // A-fragments read pre-packed from hi/lo planes; 3 independent accumulator chains.
  {
    const int d = wave & 3;
    const int kk = wave >> 2;
    const unsigned short* vph = Vph + (size_t)(d * 16 + lm) * NS + kk * 512;
    const unsigned short* vpl = Vpl + (size_t)(d * 16 + lm) * NS + kk * 512;
    const char* prow = (const char*)&sc[lm][0];
    f32x4 acc0 = (f32x4){0.f, 0.f, 0.f, 0.f};
    f32x4 acc1 = (f32x4){0.f, 0.f, 0.f, 0.f};
    f32x4 acc2 = (f32x4){0.f, 0.f, 0.f, 0.f};
#pragma unroll
    for (int ks = 0; ks < 16; ks += 2) {
      int c0 = kk * 512 + ks * 32 + lg * 8;
      short8 vh0 = *reinterpret_cast<const short8*>(vph + ks * 32 + lg * 8);
      short8 vl0 = *reinterpret_cast<const short8*>(vpl + ks * 32 + lg * 8);
      short8 vh1 = *reinterpret_cast<const short8*>(vph + (ks + 1) * 32 + lg * 8);
      short8 vl1 = *reinterpret_cast<const short8*>(vpl + (ks + 1) * 32 + lg * 8);
      short8 ph0 = *reinterpret_cast<const short8*>(prow + 2 * c0);
      short8 pl0 = *reinterpret_cast<const short8*>(prow + 4096 + 2 * c0);
      short8 ph1 = *reinterpret_cast<const short8*>(prow + 2 * (c0 + 32));
      short8 pl1 = *reinterpret_cast<const short8*>(prow + 4096 + 2 * (c0 + 32));
      acc0 = __builtin_amdgcn_mfma_f32_16x16x32_bf16(ph0, vh0, acc0, 0, 0, 0);
      acc1 = __builtin_amdgcn_mfma_f32_16x16x32_bf16(ph0, vl0, acc1, 0, 0, 0);
      acc2 = __builtin_amdgcn_mfma_f32_16x16x32_bf16(pl0, vh0, acc2, 0, 0, 0);
      acc0 = __builtin_amdgcn_mfma_f32_16x16x32_bf16(ph1, vh1, acc0, 0, 0, 0);
      acc1 = __builtin_amdgcn_mfma_f32_16x16x32_bf16(ph1, vl1, acc1, 0, 0, 0);
      acc2 = __builtin_amdgcn_mfma_f32_16x16x32_bf16(pl1, vh1, acc2, 0, 0, 0);
    }
    f32x4 pacc = (acc0 + acc1) + acc2;
#pragma unroll
    for (int r = 0; r < 4; r++) red[kk][d][lg * 4 + r][lm] = pacc[r];
  }
  __syncthreads();

  // ---- reduce k-partials and store; attn_cat [b*NS+s][1536]: hi at c, c+512; lo at c+1024
  if (wave < 4) {
    const int d = wave;
    const int b = bh >> 3, h = bh & 7;
#pragma unroll
    for (int r = 0; r < 4; r++) {
      int q = lg * 4 + r;
      float v = red[0][d][q][lm] + red[1][d][q][lm] + red[2][d][q][lm] + red[3][d][q][lm];
      int s = q0 + q;
      int c = h * 64 + d * 16 + lm;
      unsigned short hb = f2bfu(v);
      unsigned short lb = f2bfu(v - bfu2f(hb));
      size_t base = ((size_t)b * NS + s) * 1536;
      attn[base + c] = hb;
      attn[base + c + 512] = hb;
      attn[base + c + 1024] = lb;
    }
  }
}

// ---------------- launch ----------------

extern "C" void kernel_launch(void* const* d_in, const int* in_sizes, int n_in,
                              void* d_out, int out_size, void* d_ws, size_t ws_size,
                              hipStream_t stream) {
  const float* x  = (const float*)d_in[0];
  const float* Wq = (const float*)d_in[1];
  const float* bq = (const float*)d_in[2];
  const float* Wk = (const float*)d_in[3];
  const float* bk = (const float*)d_in[4];
  const float* Wv = (const float*)d_in[5];
  const float* bv = (const float*)d_in[6];
  const float* Wo = (const float*)d_in[7];
  const float* bo = (const float*)d_in[8];

  char* ws = (char*)d_ws;
  size_t off = 0;
  auto alloc = [&](size_t bytes) {
    char* p = ws + off;
    off += (bytes + 255) & ~(size_t)255;
    return p;
  };
  const int M = NB * NS;  // 8192
  unsigned short* xcat = (unsigned short*)alloc((size_t)M * 1536 * 2);  // reused as attn_cat
  unsigned short* wqC  = (unsigned short*)alloc((size_t)512 * 1536 * 2);
  unsigned short* wkC  = (unsigned short*)alloc((size_t)512 * 1536 * 2);
  unsigned short* wvC  = (unsigned short*)alloc((size_t)512 * 1536 * 2);
  unsigned short* woC  = (unsigned short*)alloc((size_t)512 * 1536 * 2);
  unsigned short* Qhi  = (unsigned short*)alloc((size_t)M * 512 * 2);
  unsigned short* Qlo  = (unsigned short*)alloc((size_t)M * 512 * 2);
  unsigned short* Khi  = (unsigned short*)alloc((size_t)M * 512 * 2);
  unsigned short* Klo  = (unsigned short*)alloc((size_t)M * 512 * 2);
  unsigned short* Vthi = (unsigned short*)alloc((size_t)M * 512 * 2);
  unsigned short* Vtlo = (unsigned short*)alloc((size_t)M * 512 * 2);
  unsigned short* attn = xcat;  // alias: xcat dead after V projection

  k_make_xcat<<<(M * 512 / 4 + 255) / 256, 256, 0, stream>>>(x, xcat, M * 512 / 4);

  dim3 tg(16, 16), tb(32, 8);
  k_transpose_split<<<tg, tb, 0, stream>>>(Wq, wqC, ND, NH * NDK);
  k_transpose_split<<<tg, tb, 0, stream>>>(Wk, wkC, ND, NH * NDK);
  k_transpose_split<<<tg, tb, 0, stream>>>(Wv, wvC, ND, NH * NDV);
  k_transpose_split<<<tg, tb, 0, stream>>>(Wo, woC, NH * NDV, ND);

  dim3 gg(512 / 64, M / 64);
  k_gemm_nt<0><<<gg, 256, 0, stream>>>(xcat, wqC, bq, Qhi, Qlo, M, 512, 1536);
  k_gemm_nt<0><<<gg, 256, 0, stream>>>(xcat, wkC, bk, Khi, Klo, M, 512, 1536);
  k_gemm_nt<2><<<gg, 256, 0, stream>>>(xcat, wvC, bv, Vthi, Vtlo, M, 512, 1536);

  k_sparse_attn<<<NB * NH * (NS / 16), 1024, 0, stream>>>(Qhi, Qlo, Khi, Klo, Vthi, Vtlo, attn);

  k_gemm_nt<3><<<gg, 256, 0, stream>>>(attn, woC, bo, d_out, nullptr, M, 512, 1536);
}

// Round 7
// 805.454 us; speedup vs baseline: 2.0298x; 1.1169x over previous
//
#include <hip/hip_runtime.h>
#include <hip/hip_bf16.h>
#include <math.h>

#define NB 4
#define NS 2048
#define ND 512
#define NH 8
#define NDK 64
#define NDV 64

typedef __attribute__((ext_vector_type(8))) short short8;
typedef __attribute__((ext_vector_type(4))) float f32x4;
typedef __attribute__((ext_vector_type(4))) unsigned int u32x4;

__device__ __forceinline__ unsigned short f2bfu(float f) {
  // round-to-nearest-even bf16 (inputs finite)
  unsigned int u = __builtin_bit_cast(unsigned int, f);
  unsigned int rounding = 0x7fffu + ((u >> 16) & 1u);
  return (unsigned short)((u + rounding) >> 16);
}
__device__ __forceinline__ float bfu2f(unsigned short u) {
  return __builtin_bit_cast(float, (unsigned int)u << 16);
}

// ---------------- prep kernels ----------------

// x [M][512] f32 -> xcat [M][1536] bf16 = [xhi | xhi | xlo]
__global__ void k_make_xcat(const float* __restrict__ in, unsigned short* __restrict__ out,
                            int n4) {
  int i = blockIdx.x * 256 + threadIdx.x;
  if (i >= n4) return;
  int row = i >> 7, col = (i & 127) * 4;  // 512/4 = 128 chunks per row
  float4 f = reinterpret_cast<const float4*>(in)[i];
  ushort4 h, l;
  h.x = f2bfu(f.x); h.y = f2bfu(f.y); h.z = f2bfu(f.z); h.w = f2bfu(f.w);
  l.x = f2bfu(f.x - bfu2f(h.x)); l.y = f2bfu(f.y - bfu2f(h.y));
  l.z = f2bfu(f.z - bfu2f(h.z)); l.w = f2bfu(f.w - bfu2f(h.w));
  ushort4* o = reinterpret_cast<ushort4*>(out + (size_t)row * 1536);
  o[col / 4] = h;
  o[(col + 512) / 4] = h;
  o[(col + 1024) / 4] = l;
}

// W [R][C] f32 -> Wcat [C][3R] bf16 rows = [Whi^T | Wlo^T | Whi^T]
__global__ void k_transpose_split(const float* __restrict__ src, unsigned short* __restrict__ dst,
                                  int R, int C) {
  __shared__ float t[32][33];
  int bx = blockIdx.x * 32, by = blockIdx.y * 32;
  int tx = threadIdx.x, ty = threadIdx.y;
  for (int i = 0; i < 32; i += 8)
    t[ty + i][tx] = src[(size_t)(by + ty + i) * C + bx + tx];
  __syncthreads();
  for (int i = 0; i < 32; i += 8) {
    float f = t[tx][ty + i];
    unsigned short h = f2bfu(f);
    unsigned short l = f2bfu(f - bfu2f(h));
    size_t base = (size_t)(bx + ty + i) * (3 * R) + by + tx;
    dst[base] = h;
    dst[base + R] = l;
    dst[base + 2 * R] = h;
  }
}

// ---------------- NT MFMA GEMM: C = A * Bt^T + bias ----------------
template <int MODE>
__global__ __launch_bounds__(256) void k_gemm_nt(
    const unsigned short* __restrict__ A, const unsigned short* __restrict__ Bt,
    const float* __restrict__ bias, void* __restrict__ outp, unsigned short* __restrict__ outlo,
    int M, int N, int K) {
  __shared__ __align__(16) unsigned short As[64][88];
  __shared__ __align__(16) unsigned short Bs[64][88];
  const int tid = threadIdx.x;
  const int m0 = blockIdx.y * 64;
  const int n0 = blockIdx.x * 64;
  const int wave = tid >> 6, lane = tid & 63;
  const int lm = lane & 15, lg = lane >> 4;

  f32x4 acc[4];
  for (int n = 0; n < 4; n++) acc[n] = (f32x4){0.f, 0.f, 0.f, 0.f};

  for (int k0 = 0; k0 < K; k0 += 64) {
    for (int it = 0; it < 2; it++) {
      int c = tid + it * 256;
      int row = c >> 3, col = (c & 7) * 8;
      *reinterpret_cast<short8*>(&As[row][col]) =
          *reinterpret_cast<const short8*>(A + (size_t)(m0 + row) * K + k0 + col);
      *reinterpret_cast<short8*>(&Bs[row][col]) =
          *reinterpret_cast<const short8*>(Bt + (size_t)(n0 + row) * K + k0 + col);
    }
    __syncthreads();
#pragma unroll
    for (int ks = 0; ks < 2; ks++) {
      short8 a = *reinterpret_cast<const short8*>(&As[wave * 16 + lm][ks * 32 + lg * 8]);
#pragma unroll
      for (int n = 0; n < 4; n++) {
        short8 b = *reinterpret_cast<const short8*>(&Bs[n * 16 + lm][ks * 32 + lg * 8]);
        acc[n] = __builtin_amdgcn_mfma_f32_16x16x32_bf16(a, b, acc[n], 0, 0, 0);
      }
    }
    __syncthreads();
  }

#pragma unroll
  for (int n = 0; n < 4; n++) {
    int gn = n0 + n * 16 + lm;
    float bv = bias[gn];
#pragma unroll
    for (int r = 0; r < 4; r++) {
      int gm = m0 + wave * 16 + lg * 4 + r;
      float v = acc[n][r] + bv;
      if (MODE == 3) {
        reinterpret_cast<float*>(outp)[(size_t)gm * ND + gn] = v;
      } else {
        int b = gm >> 11, s = gm & (NS - 1);
        int h = gn >> 6, d = gn & 63;
        unsigned short hb = f2bfu(v);
        unsigned short lb = f2bfu(v - bfu2f(hb));
        size_t idx;
        if (MODE == 0)
          idx = (((size_t)b * NH + h) * NS + s) * NDK + d;
        else
          idx = (((size_t)b * NH + h) * NDV + d) * NS + s;
        reinterpret_cast<unsigned short*>(outp)[idx] = hb;
        outlo[idx] = lb;
      }
    }
  }
}

// ---------------- fused sparse attention: register-resident scores ----------------
// 512 threads (8 waves), 2 blocks/CU. One block = one (b,h) + 16 q rows.
// Wave w owns kv slice [w*256, w*256+256). Swapped QK^T (mfma(K,Q)): every lane's
// 64 scores belong to q = lane&15, kv = w*256 + kt*16 + lg*4 + r.
__global__ __launch_bounds__(512, 4) void k_sparse_attn(
    const unsigned short* __restrict__ Qh, const unsigned short* __restrict__ Ql,
    const unsigned short* __restrict__ Kh, const unsigned short* __restrict__ Kl,
    const unsigned short* __restrict__ Vth, const unsigned short* __restrict__ Vtl,
    unsigned short* __restrict__ attn) {
  __shared__ float part[5][8][16];                // [round][wave][q] reduction partials
  __shared__ __align__(16) float red[8][16][68];  // [wave][q][dv] PV partials (+4 pad)

  const int tid = threadIdx.x;
  const int wave = tid >> 6, lane = tid & 63;
  const int lm = lane & 15, lg = lane >> 4;

  // bijective XCD swizzle: 4096 wgs -> XCD x gets logical ids [x*512, x*512+512)
  const int orig = blockIdx.x;
  const int blk = (orig & 7) * 512 + (orig >> 3);
  const int qt = blk & (NS / 16 - 1);
  const int bh = blk >> 7;  // NS/16 == 128
  const int q0 = qt * 16;

  const size_t qoff = ((size_t)bh * NS + q0) * NDK;
  const unsigned short* Kph = Kh + (size_t)bh * NS * NDK;
  const unsigned short* Kpl = Kl + (size_t)bh * NS * NDK;
  const unsigned short* Vph = Vth + (size_t)bh * NDV * NS;
  const unsigned short* Vpl = Vtl + (size_t)bh * NDV * NS;
  const int kvbase = wave * 256;

  // ---- QK^T into registers ----
  f32x4 st[16];
  {
    short8 qh0 = *reinterpret_cast<const short8*>(Qh + qoff + lm * NDK + lg * 8);
    short8 qh1 = *reinterpret_cast<const short8*>(Qh + qoff + lm * NDK + 32 + lg * 8);
    short8 ql0 = *reinterpret_cast<const short8*>(Ql + qoff + lm * NDK + lg * 8);
    short8 ql1 = *reinterpret_cast<const short8*>(Ql + qoff + lm * NDK + 32 + lg * 8);
#pragma unroll
    for (int kt = 0; kt < 16; kt++) {
      size_t ko = (size_t)(kvbase + kt * 16) * NDK;
      const unsigned short* kh = Kph + ko + lm * NDK + lg * 8;
      const unsigned short* kl = Kpl + ko + lm * NDK + lg * 8;
      short8 ah0 = *reinterpret_cast<const short8*>(kh);
      short8 ah1 = *reinterpret_cast<const short8*>(kh + 32);
      short8 al0 = *reinterpret_cast<const short8*>(kl);
      short8 al1 = *reinterpret_cast<const short8*>(kl + 32);
      f32x4 a0 = (f32x4){0.f, 0.f, 0.f, 0.f};
      f32x4 a1 = (f32x4){0.f, 0.f, 0.f, 0.f};
      a0 = __builtin_amdgcn_mfma_f32_16x16x32_bf16(ah0, qh0, a0, 0, 0, 0);
      a1 = __builtin_amdgcn_mfma_f32_16x16x32_bf16(ah1, qh1, a1, 0, 0, 0);
      a0 = __builtin_amdgcn_mfma_f32_16x16x32_bf16(al0, qh0, a0, 0, 0, 0);
      a1 = __builtin_amdgcn_mfma_f32_16x16x32_bf16(al1, qh1, a1, 0, 0, 0);
      a0 = __builtin_amdgcn_mfma_f32_16x16x32_bf16(ah0, ql0, a0, 0, 0, 0);
      a1 = __builtin_amdgcn_mfma_f32_16x16x32_bf16(ah1, ql1, a1, 0, 0, 0);
      st[kt] = (a0 + a1) * 0.125f;  // 1/sqrt(64)
    }
  }

  // ---- softmax + sparsification: intra-lane -> shfl(lg) -> tiny LDS cross-wave ----
  float cut, inv;
  {
    float m = -1e30f;
#pragma unroll
    for (int kt = 0; kt < 16; kt++)
      m = fmaxf(m, fmaxf(fmaxf(st[kt][0], st[kt][1]), fmaxf(st[kt][2], st[kt][3])));
    m = fmaxf(m, __shfl_xor(m, 16));
    m = fmaxf(m, __shfl_xor(m, 32));
    if (lg == 0) part[0][wave][lm] = m;
    __syncthreads();
    float gm = -1e30f;
#pragma unroll
    for (int w = 0; w < 8; w++) gm = fmaxf(gm, part[0][w][lm]);

    float E = 0.f;
#pragma unroll
    for (int kt = 0; kt < 16; kt++) {
#pragma unroll
      for (int j = 0; j < 4; j++) {
        float e = __expf(st[kt][j] - gm);
        st[kt][j] = e;
        E += e;
      }
    }
    E += __shfl_xor(E, 16);
    E += __shfl_xor(E, 32);
    if (lg == 0) part[1][wave][lm] = E;
    __syncthreads();
    float gE = 0.f;
#pragma unroll
    for (int w = 0; w < 8; w++) gE += part[1][w][lm];

    const float thr[3] = {1.0f / 2048.0f, 1.0f / (0.6f * 2048.0f), 1.0f / (0.36f * 2048.0f)};
    float Dd = 1.0f;
    cut = 0.f;
#pragma unroll
    for (int t = 0; t < 3; t++) {
      cut = fmaxf(cut, thr[t] * Dd * gE);
      float S = 0.f;
#pragma unroll
      for (int kt = 0; kt < 16; kt++) {
#pragma unroll
        for (int j = 0; j < 4; j++) S += (st[kt][j] >= cut) ? st[kt][j] : 0.f;
      }
      S += __shfl_xor(S, 16);
      S += __shfl_xor(S, 32);
      if (lg == 0) part[2 + t][wave][lm] = S;
      __syncthreads();
      float gS = 0.f;
#pragma unroll
      for (int w = 0; w < 8; w++) gS += part[2 + t][w][lm];
      Dd = gS / gE + 1e-9f * Dd;
    }
    inv = 1.0f / (gE * Dd);  // final w = e * inv on kept set
  }

  // ---- convert kept weights to packed bf16 hi/lo words (once per value) ----
  unsigned int Hp[16][2], Lp[16][2];
#pragma unroll
  for (int kt = 0; kt < 16; kt++) {
#pragma unroll
    for (int rp = 0; rp < 2; rp++) {
      float w0 = st[kt][2 * rp], w1 = st[kt][2 * rp + 1];
      w0 = (w0 >= cut) ? w0 * inv : 0.f;
      w1 = (w1 >= cut) ? w1 * inv : 0.f;
      unsigned int h0 = f2bfu(w0), h1 = f2bfu(w1);
      Hp[kt][rp] = h0 | (h1 << 16);
      unsigned int l0 = f2bfu(w0 - bfu2f((unsigned short)h0));
      unsigned int l1 = f2bfu(w1 - bfu2f((unsigned short)h1));
      Lp[kt][rp] = l0 | (l1 << 16);
    }
  }

  // ---- PV: A-frags via cross-lane shuffle; wave covers its kv slice, all 64 dv ----
  {
    const int e_lane = lm + 32 * (lg & 1);
    const int o_lane = e_lane + 16;
    const bool selB = (lane & 32) != 0;
    f32x4 acc[4];
#pragma unroll
    for (int dt = 0; dt < 4; dt++) acc[dt] = (f32x4){0.f, 0.f, 0.f, 0.f};
#pragma unroll
    for (int wi = 0; wi < 8; wi++) {
      unsigned int a0 = (unsigned)__shfl((int)Hp[2 * wi][0], e_lane);
      unsigned int a1 = (unsigned)__shfl((int)Hp[2 * wi][1], e_lane);
      unsigned int a2 = (unsigned)__shfl((int)Hp[2 * wi][0], o_lane);
      unsigned int a3 = (unsigned)__shfl((int)Hp[2 * wi][1], o_lane);
      unsigned int b0 = (unsigned)__shfl((int)Hp[2 * wi + 1][0], e_lane);
      unsigned int b1 = (unsigned)__shfl((int)Hp[2 * wi + 1][1], e_lane);
      unsigned int b2 = (unsigned)__shfl((int)Hp[2 * wi + 1][0], o_lane);
      unsigned int b3 = (unsigned)__shfl((int)Hp[2 * wi + 1][1], o_lane);
      u32x4 hw = (u32x4){selB ? b0 : a0, selB ? b1 : a1, selB ? b2 : a2, selB ? b3 : a3};
      a0 = (unsigned)__shfl((int)Lp[2 * wi][0], e_lane);
      a1 = (unsigned)__shfl((int)Lp[2 * wi][1], e_lane);
      a2 = (unsigned)__shfl((int)Lp[2 * wi][0], o_lane);
      a3 = (unsigned)__shfl((int)Lp[2 * wi][1], o_lane);
      b0 = (unsigned)__shfl((int)Lp[2 * wi + 1][0], e_lane);
      b1 = (unsigned)__shfl((int)Lp[2 * wi + 1][1], e_lane);
      b2 = (unsigned)__shfl((int)Lp[2 * wi + 1][0], o_lane);
      b3 = (unsigned)__shfl((int)Lp[2 * wi + 1][1], o_lane);
      u32x4 lw = (u32x4){selB ? b0 : a0, selB ? b1 : a1, selB ? b2 : a2, selB ? b3 : a3};
      short8 Ah = __builtin_bit_cast(short8, hw);
      short8 Al = __builtin_bit_cast(short8, lw);
      const int co = kvbase + wi * 32 + lg * 8;
#pragma unroll
      for (int dt = 0; dt < 4; dt++) {
        short8 V0 = *reinterpret_cast<const short8*>(Vph + (size_t)(dt * 16 + lm) * NS + co);
        short8 V1 = *reinterpret_cast<const short8*>(Vpl + (size_t)(dt * 16 + lm) * NS + co);
        acc[dt] = __builtin_amdgcn_mfma_f32_16x16x32_bf16(Ah, V0, acc[dt], 0, 0, 0);
        acc[dt] = __builtin_amdgcn_mfma_f32_16x16x32_bf16(Ah, V1, acc[dt], 0, 0, 0);
        acc[dt] = __builtin_amdgcn_mfma_f32_16x16x32_bf16(Al, V0, acc[dt], 0, 0, 0);
      }
    }
#pragma unroll
    for (int dt = 0; dt < 4; dt++)
#pragma unroll
      for (int rr = 0; rr < 4; rr++) red[wave][lg * 4 + rr][dt * 16 + lm] = acc[dt][rr];
  }
  __syncthreads();

  // ---- reduce 8 wave-partials; write attn_cat [b*NS+s][1536] ----
  {
    const int q = tid >> 5;          // 0..15
    const int dv0 = (tid & 31) * 2;  // 0..62
    const int b = bh >> 3, h = bh & 7;
    const int s = q0 + q;
    size_t base = ((size_t)b * NS + s) * 1536;
#pragma unroll
    for (int k2 = 0; k2 < 2; k2++) {
      int dv = dv0 + k2;
      float v = 0.f;
#pragma unroll
      for (int w = 0; w < 8; w++) v += red[w][q][dv];
      int c = h * 64 + dv;
      unsigned short hb = f2bfu(v);
      unsigned short lb = f2bfu(v - bfu2f(hb));
      attn[base + c] = hb;
      attn[base + c + 512] = hb;
      attn[base + c + 1024] = lb;
    }
  }
}

// ---------------- launch ----------------

extern "C" void kernel_launch(void* const* d_in, const int* in_sizes, int n_in,
                              void* d_out, int out_size, void* d_ws, size_t ws_size,
                              hipStream_t stream) {
  const float* x  = (const float*)d_in[0];
  const float* Wq = (const float*)d_in[1];
  const float* bq = (const float*)d_in[2];
  const float* Wk = (const float*)d_in[3];
  const float* bk = (const float*)d_in[4];
  const float* Wv = (const float*)d_in[5];
  const float* bv = (const float*)d_in[6];
  const float* Wo = (const float*)d_in[7];
  const float* bo = (const float*)d_in[8];

  char* ws = (char*)d_ws;
  size_t off = 0;
  auto alloc = [&](size_t bytes) {
    char* p = ws + off;
    off += (bytes + 255) & ~(size_t)255;
    return p;
  };
  const int M = NB * NS;  // 8192
  unsigned short* xcat = (unsigned short*)alloc((size_t)M * 1536 * 2);  // reused as attn_cat
  unsigned short* wqC  = (unsigned short*)alloc((size_t)512 * 1536 * 2);
  unsigned short* wkC  = (unsigned short*)alloc((size_t)512 * 1536 * 2);
  unsigned short* wvC  = (unsigned short*)alloc((size_t)512 * 1536 * 2);
  unsigned short* woC  = (unsigned short*)alloc((size_t)512 * 1536 * 2);
  unsigned short* Qhi  = (unsigned short*)alloc((size_t)M * 512 * 2);
  unsigned short* Qlo  = (unsigned short*)alloc((size_t)M * 512 * 2);
  unsigned short* Khi  = (unsigned short*)alloc((size_t)M * 512 * 2);
  unsigned short* Klo  = (unsigned short*)alloc((size_t)M * 512 * 2);
  unsigned short* Vthi = (unsigned short*)alloc((size_t)M * 512 * 2);
  unsigned short* Vtlo = (unsigned short*)alloc((size_t)M * 512 * 2);
  unsigned short* attn = xcat;  // alias: xcat dead after V projection

  k_make_xcat<<<(M * 512 / 4 + 255) / 256, 256, 0, stream>>>(x, xcat, M * 512 / 4);

  dim3 tg(16, 16), tb(32, 8);
  k_transpose_split<<<tg, tb, 0, stream>>>(Wq, wqC, ND, NH * NDK);
  k_transpose_split<<<tg, tb, 0, stream>>>(Wk, wkC, ND, NH * NDK);
  k_transpose_split<<<tg, tb, 0, stream>>>(Wv, wvC, ND, NH * NDV);
  k_transpose_split<<<tg, tb, 0, stream>>>(Wo, woC, NH * NDV, ND);

  dim3 gg(512 / 64, M / 64);
  k_gemm_nt<0><<<gg, 256, 0, stream>>>(xcat, wqC, bq, Qhi, Qlo, M, 512, 1536);
  k_gemm_nt<0><<<gg, 256, 0, stream>>>(xcat, wkC, bk, Khi, Klo, M, 512, 1536);
  k_gemm_nt<2><<<gg, 256, 0, stream>>>(xcat, wvC, bv, Vthi, Vtlo, M, 512, 1536);

  k_sparse_attn<<<NB * NH * (NS / 16), 512, 0, stream>>>(Qhi, Qlo, Khi, Klo, Vthi, Vtlo, attn);

  k_gemm_nt<3><<<gg, 256, 0, stream>>>(attn, woC, bo, d_out, nullptr, M, 512, 1536);
}